// Round 3
// baseline (369.843 us; speedup 1.0000x reference)
//
#include <hip/hip_runtime.h>
#include <cstdint>
#include <cstddef>

#define NFEAT 512
#define NH1   256
#define NH2   128

#define SCAN_BLOCK 256
#define SCAN_ELEMS 4
#define SCAN_TILE  (SCAN_BLOCK * SCAN_ELEMS)   // 1024

typedef __attribute__((ext_vector_type(8))) short short8;
typedef __attribute__((ext_vector_type(4))) float float4v;

__device__ __forceinline__ unsigned short f2bf(float f) {
    unsigned int u = __float_as_uint(f);
    u += 0x7fffu + ((u >> 16) & 1u);   // round-to-nearest-even
    return (unsigned short)(u >> 16);
}
__device__ __forceinline__ float bf2f(unsigned short u) {
    return __uint_as_float(((unsigned int)u) << 16);
}

__device__ __forceinline__ void load_lds16(const void* g, void* l) {
    __builtin_amdgcn_global_load_lds(
        (const __attribute__((address_space(1))) void*)g,
        (__attribute__((address_space(3))) void*)l, 16, 0, 0);
}

// ---------------- degree count (global atomics) + weight cvt, one dispatch ----
__global__ __launch_bounds__(256) void k_deg_cvtw(
    const int* __restrict__ dst, int* __restrict__ degi,
    const float* __restrict__ W1, unsigned short* __restrict__ W1t,
    const float* __restrict__ W2, unsigned short* __restrict__ W2t,
    int E, int degBlocks) {
    const int b = blockIdx.x;
    if (b < degBlocks) {
        const int e = b * 256 + (int)threadIdx.x;
        if (e < E) atomicAdd(&degi[dst[e]], 1);
    } else {
        const int i = (b - degBlocks) * 256 + (int)threadIdx.x;
        const int T1 = NFEAT * NH1;
        const int T2 = NH1 * NH2;
        if (i < T1) {
            const int k = i / NH1, n = i % NH1;
            W1t[(size_t)n * NFEAT + k] = f2bf(W1[i]);
        } else if (i < T1 + T2) {
            const int j = i - T1;
            const int k = j / NH2, n = j % NH2;
            W2t[(size_t)n * NH1 + k] = f2bf(W2[j]);
        }
    }
}

// ---- three-phase exclusive scan over degi[0..N) -> row_start (+ fused dinv) ----
__global__ __launch_bounds__(SCAN_BLOCK) void k_scan1(
    const int* __restrict__ degi, int* __restrict__ blocksums,
    float* __restrict__ dinv, int N) {
    __shared__ int red[SCAN_BLOCK];
    const int t = threadIdx.x;
    const int base = blockIdx.x * SCAN_TILE + t * SCAN_ELEMS;
    int s = 0;
#pragma unroll
    for (int i = 0; i < SCAN_ELEMS; ++i) {
        const int idx = base + i;
        if (idx < N) {
            const int dg = degi[idx];
            s += dg;
            dinv[idx] = rsqrtf((float)(dg + 1));   // +1 = self-loop
        }
    }
    red[t] = s;
    __syncthreads();
    for (int off = SCAN_BLOCK / 2; off > 0; off >>= 1) {
        if (t < off) red[t] += red[t + off];
        __syncthreads();
    }
    if (t == 0) blocksums[blockIdx.x] = red[0];
}

__global__ __launch_bounds__(1024) void k_scan2(
    const int* __restrict__ blocksums, int* __restrict__ blockoffs,
    int* __restrict__ row_start, int nb, int N) {
    __shared__ int sm[1024];
    const int t = threadIdx.x;
    const int v = (t < nb) ? blocksums[t] : 0;
    sm[t] = v;
    __syncthreads();
    for (int off = 1; off < 1024; off <<= 1) {
        const int x = (t >= off) ? sm[t - off] : 0;
        __syncthreads();
        sm[t] += x;
        __syncthreads();
    }
    if (t < nb) blockoffs[t] = sm[t] - v;
    if (t == 1023) row_start[N] = sm[1023];
}

__global__ __launch_bounds__(SCAN_BLOCK) void k_scan3(
    const int* __restrict__ degi, const int* __restrict__ blockoffs,
    int* __restrict__ row_start, int N) {
    __shared__ int tsum[SCAN_BLOCK];
    const int t = threadIdx.x;
    const int base = blockIdx.x * SCAN_TILE + t * SCAN_ELEMS;
    int v[SCAN_ELEMS];
    int s = 0;
#pragma unroll
    for (int i = 0; i < SCAN_ELEMS; ++i) {
        const int idx = base + i;
        v[i] = (idx < N) ? degi[idx] : 0;
        s += v[i];
    }
    tsum[t] = s;
    __syncthreads();
    for (int off = 1; off < SCAN_BLOCK; off <<= 1) {
        const int x = (t >= off) ? tsum[t - off] : 0;
        __syncthreads();
        tsum[t] += x;
        __syncthreads();
    }
    int excl = blockoffs[blockIdx.x] + tsum[t] - s;
#pragma unroll
    for (int i = 0; i < SCAN_ELEMS; ++i) {
        const int idx = base + i;
        if (idx < N) row_start[idx] = excl;
        excl += v[i];
    }
}

// ---- edge placement: row_start doubles as cursor (ends up SHIFTED by one:
//      after this kernel row_start[d] == original row_start[d+1]) ----
__global__ __launch_bounds__(256) void k_place2(
    const int* __restrict__ src, const int* __restrict__ dst,
    int* __restrict__ cursor /* = row_start, mutated */,
    int* __restrict__ csr_src, int E) {
    const int e = blockIdx.x * 256 + (int)threadIdx.x;
    if (e < E) {
        const int d = dst[e];
        const int p = atomicAdd(&cursor[d], 1);
        csr_src[p] = src[e];
    }
}

// ---------------- fused layer-1 GEMM: h = bf16((x*dinv) @ W1) ----------------
// 128x256 tile, 8 waves (512 thr). A is reg-staged f32 -> *dinv -> bf16 -> LDS;
// B (W1t, 256x512 bf16 n-major) via global_load_lds. Single column block: A read once.
__global__ __launch_bounds__(512) void gemm_x_fused(
    const float* __restrict__ x, const float* __restrict__ dinv,
    const unsigned short* __restrict__ Bt, unsigned short* __restrict__ C,
    int Nrows, int K) {
    __shared__ unsigned short As[128 * 32];   //  8 KB
    __shared__ unsigned short Bs[256 * 32];   // 16 KB
    const int t    = threadIdx.x;
    const int wave = t >> 6, lane = t & 63;
    const int row0 = blockIdx.x * 128;
    const int quad = lane >> 4, l15 = lane & 15;
    const int wm = (wave >> 2) * 64;          // 0 / 64
    const int wn = (wave & 3) * 64;           // 0 / 64 / 128 / 192

    // A staging: thread t -> row t>>2 (0..127), k-offset (t&3)*8 (8 f32)
    const int arow = t >> 2;
    const int ak   = (t & 3) * 8;
    const int gr   = (row0 + arow < Nrows) ? row0 + arow : Nrows - 1;  // clamp pad rows
    const float wd = dinv[gr];
    const float* gx = x + (size_t)gr * K + ak;
    unsigned short* lA = &As[arow * 32 + ak];                 // byte off = t*16 (linear)

    // B staging: two global_load_lds segs; linear LDS [256][32] matches t*16 layout
    const int brow = t >> 2;                  // 0..127 (seg2: +128)
    const int bk   = (t & 3) * 8;
    const unsigned short* gB0 = Bt + (size_t)brow * K + bk;
    const unsigned short* gB1 = Bt + (size_t)(128 + brow) * K + bk;
    unsigned short* lB0 = &Bs[wave * 512];            // wave-uniform base + lane*16
    unsigned short* lB1 = &Bs[128 * 32 + wave * 512];

    float4v acc[4][4] = {};

    for (int k0 = 0; k0 < K; k0 += 32) {
        __syncthreads();
        load_lds16(gB0 + k0, lB0);
        load_lds16(gB1 + k0, lB1);
        const float4 v0 = *(const float4*)(gx + k0);
        const float4 v1 = *(const float4*)(gx + k0 + 4);
        short8 o;
        o[0] = (short)f2bf(v0.x * wd); o[1] = (short)f2bf(v0.y * wd);
        o[2] = (short)f2bf(v0.z * wd); o[3] = (short)f2bf(v0.w * wd);
        o[4] = (short)f2bf(v1.x * wd); o[5] = (short)f2bf(v1.y * wd);
        o[6] = (short)f2bf(v1.z * wd); o[7] = (short)f2bf(v1.w * wd);
        *(short8*)lA = o;                                   // 16B ds_write
        __syncthreads();

        short8 a[4], b[4];
#pragma unroll
        for (int i = 0; i < 4; ++i) {
            a[i] = *(const short8*)&As[(wm + i * 16 + l15) * 32 + quad * 8];
            b[i] = *(const short8*)&Bs[(wn + i * 16 + l15) * 32 + quad * 8];
        }
#pragma unroll
        for (int mt = 0; mt < 4; ++mt)
#pragma unroll
            for (int nt = 0; nt < 4; ++nt)
                acc[mt][nt] = __builtin_amdgcn_mfma_f32_16x16x32_bf16(
                    a[mt], b[nt], acc[mt][nt], 0, 0, 0);
    }

    // C/D layout: col = lane&15, row = (lane>>4)*4 + reg   [m89-verified]
#pragma unroll
    for (int mt = 0; mt < 4; ++mt) {
#pragma unroll
        for (int nt = 0; nt < 4; ++nt) {
            const int c = wn + nt * 16 + l15;
#pragma unroll
            for (int r = 0; r < 4; ++r) {
                const int row = row0 + wm + mt * 16 + quad * 4 + r;
                C[(size_t)row * NH1 + c] = f2bf(acc[mt][nt][r]);
            }
        }
    }
}

// ---------------- bf16 MFMA GEMM (layer 2) ----------------
__global__ __launch_bounds__(256) void gemm_bf16(
    const unsigned short* __restrict__ A, const unsigned short* __restrict__ Bt,
    unsigned short* __restrict__ C, int N, int K) {
    __shared__ unsigned short As[128 * 32];
    __shared__ unsigned short Bs[128 * 32];
    const int t    = threadIdx.x;
    const int wave = t >> 6, lane = t & 63;
    const int row0 = blockIdx.y * 128, col0 = blockIdx.x * 128;
    const int wm = (wave >> 1) * 64, wn = (wave & 1) * 64;
    const int sr = lane >> 2;
    const int sk = (lane & 3) * 8;
    const int quad = lane >> 4, l15 = lane & 15;

    const int ca = wave * 2;
    const unsigned short* gA0 = A  + (size_t)(row0 + ca * 16 + sr) * K + sk;
    const unsigned short* gA1 = gA0 + (size_t)16 * K;
    const unsigned short* gB0 = Bt + (size_t)(col0 + ca * 16 + sr) * K + sk;
    const unsigned short* gB1 = gB0 + (size_t)16 * K;
    unsigned short* lA0 = &As[ca * 512];
    unsigned short* lA1 = &As[(ca + 1) * 512];
    unsigned short* lB0 = &Bs[ca * 512];
    unsigned short* lB1 = &Bs[(ca + 1) * 512];

    float4v acc[4][4] = {};

    for (int k0 = 0; k0 < K; k0 += 32) {
        __syncthreads();
        load_lds16(gA0 + k0, lA0);
        load_lds16(gA1 + k0, lA1);
        load_lds16(gB0 + k0, lB0);
        load_lds16(gB1 + k0, lB1);
        __syncthreads();

        short8 a[4], b[4];
#pragma unroll
        for (int i = 0; i < 4; ++i) {
            a[i] = *(const short8*)&As[(wm + i * 16 + l15) * 32 + quad * 8];
            b[i] = *(const short8*)&Bs[(wn + i * 16 + l15) * 32 + quad * 8];
        }
#pragma unroll
        for (int mt = 0; mt < 4; ++mt)
#pragma unroll
            for (int nt = 0; nt < 4; ++nt)
                acc[mt][nt] = __builtin_amdgcn_mfma_f32_16x16x32_bf16(
                    a[mt], b[nt], acc[mt][nt], 0, 0, 0);
    }

    // C/D layout: col = lane&15, row = (lane>>4)*4 + reg   [m89-verified]
#pragma unroll
    for (int mt = 0; mt < 4; ++mt) {
#pragma unroll
        for (int nt = 0; nt < 4; ++nt) {
            const int c = col0 + wn + nt * 16 + l15;
#pragma unroll
            for (int r = 0; r < 4; ++r) {
                const int row = row0 + wm + mt * 16 + quad * 4 + r;
                C[(size_t)row * N + c] = f2bf(acc[mt][nt][r]);
            }
        }
    }
}

// ---------------- CSR gather aggregation (bf16 features, pre-scaled rows) ----
// NOTE: row_start is the post-place SHIFTED array: row d spans
//       [ (d ? rs[d-1] : 0), rs[d] ).
template <int F, bool RELU, bool OUTF32>
__global__ __launch_bounds__(256) void k_gather(
    const int* __restrict__ row_start, const int* __restrict__ csr_src,
    const float* __restrict__ dinv, const unsigned short* __restrict__ h,
    const float* __restrict__ bias, unsigned short* __restrict__ ob,
    float* __restrict__ of, int N) {
    const int gid  = blockIdx.x * blockDim.x + threadIdx.x;
    const int node = gid >> 6;
    const int lane = gid & 63;
    if (node >= N) return;

    constexpr int EL = F / 64;           // 4 (F=256) or 2 (F=128)
    const float wd = dinv[node];
    const int je = row_start[node];
    const int jb = (node == 0) ? 0 : row_start[node - 1];
    const unsigned short* hl = h + (size_t)lane * EL;

    float acc[EL];
    {   // self-loop term (h already dinv-scaled)
        const unsigned short* hp = hl + (size_t)node * F;
        if (EL == 4) {
            const ushort4 v = *(const ushort4*)hp;
            acc[0] = bf2f(v.x); acc[1] = bf2f(v.y);
            acc[2] = bf2f(v.z); acc[3] = bf2f(v.w);
        } else {
            const ushort2 v = *(const ushort2*)hp;
            acc[0] = bf2f(v.x); acc[1] = bf2f(v.y);
        }
    }

    for (int j0 = jb; j0 < je; j0 += 64) {
        int jj = j0 + lane;
        if (jj >= je) jj = je - 1;
        const int myi = csr_src[jj];
        const int rem = je - j0;
        const int cnt = rem < 64 ? rem : 64;
        int i = 0;
        for (; i + 4 <= cnt; i += 4) {   // 4 independent row loads in flight
            const int s0 = __shfl(myi, i + 0);
            const int s1 = __shfl(myi, i + 1);
            const int s2 = __shfl(myi, i + 2);
            const int s3 = __shfl(myi, i + 3);
            if (EL == 4) {
                const ushort4 v0 = *(const ushort4*)(hl + (size_t)s0 * F);
                const ushort4 v1 = *(const ushort4*)(hl + (size_t)s1 * F);
                const ushort4 v2 = *(const ushort4*)(hl + (size_t)s2 * F);
                const ushort4 v3 = *(const ushort4*)(hl + (size_t)s3 * F);
                acc[0] += bf2f(v0.x) + bf2f(v1.x) + bf2f(v2.x) + bf2f(v3.x);
                acc[1] += bf2f(v0.y) + bf2f(v1.y) + bf2f(v2.y) + bf2f(v3.y);
                acc[2] += bf2f(v0.z) + bf2f(v1.z) + bf2f(v2.z) + bf2f(v3.z);
                acc[3] += bf2f(v0.w) + bf2f(v1.w) + bf2f(v2.w) + bf2f(v3.w);
            } else {
                const ushort2 v0 = *(const ushort2*)(hl + (size_t)s0 * F);
                const ushort2 v1 = *(const ushort2*)(hl + (size_t)s1 * F);
                const ushort2 v2 = *(const ushort2*)(hl + (size_t)s2 * F);
                const ushort2 v3 = *(const ushort2*)(hl + (size_t)s3 * F);
                acc[0] += bf2f(v0.x) + bf2f(v1.x) + bf2f(v2.x) + bf2f(v3.x);
                acc[1] += bf2f(v0.y) + bf2f(v1.y) + bf2f(v2.y) + bf2f(v3.y);
            }
        }
        for (; i < cnt; ++i) {
            const int s = __shfl(myi, i);
            const unsigned short* hp = hl + (size_t)s * F;
            if (EL == 4) {
                const ushort4 v = *(const ushort4*)hp;
                acc[0] += bf2f(v.x); acc[1] += bf2f(v.y);
                acc[2] += bf2f(v.z); acc[3] += bf2f(v.w);
            } else {
                const ushort2 v = *(const ushort2*)hp;
                acc[0] += bf2f(v.x); acc[1] += bf2f(v.y);
            }
        }
    }

#pragma unroll
    for (int i = 0; i < EL; ++i) {
        float v = fmaf(acc[i], wd, bias[lane * EL + i]);
        if (OUTF32) {
            of[(size_t)node * F + lane * EL + i] = v;
        } else {
            if (RELU) v = fmaxf(v, 0.f);
            ob[(size_t)node * F + lane * EL + i] = f2bf(v * wd);  // pre-scale for next layer
        }
    }
}

extern "C" void kernel_launch(void* const* d_in, const int* in_sizes, int n_in,
                              void* d_out, int out_size, void* d_ws, size_t ws_size,
                              hipStream_t stream) {
    const float* x   = (const float*)d_in[0];
    const int*   ei  = (const int*)d_in[1];
    const float* W1  = (const float*)d_in[2];
    const float* b1  = (const float*)d_in[3];
    const float* W2  = (const float*)d_in[4];
    const float* b2  = (const float*)d_in[5];
    float*       out = (float*)d_out;

    const int N = in_sizes[0] / NFEAT;           // 50000
    const int E = in_sizes[1] / 2;               // 800000
    const int Mp = ((N + 127) / 128) * 128;      // 50048
    const int* srcp = ei;
    const int* dstp = ei + E;
    const int nScanBlocks = (N + SCAN_TILE - 1) / SCAN_TILE;   // 49

    // workspace layout (256B aligned chunks)
    char* wsb = (char*)d_ws;
    auto take = [&](size_t bytes) {
        char* p = wsb;
        wsb += (bytes + 255) & ~(size_t)255;
        return p;
    };
    int*   degi      = (int*)take((size_t)N * 4);
    int*   row_start = (int*)take((size_t)(N + 1) * 4);
    int*   csr_src   = (int*)take((size_t)E * 4);
    int*   blocksums = (int*)take((size_t)1024 * 4);
    int*   blockoffs = (int*)take((size_t)1024 * 4);
    float* dinv      = (float*)take((size_t)N * 4);
    unsigned short* h2r = (unsigned short*)take((size_t)Mp * NH2 * 2);   // h2
    unsigned short* W1t = (unsigned short*)take((size_t)NH1 * NFEAT * 2);
    unsigned short* W2t = (unsigned short*)take((size_t)NH2 * NH1 * 2);
    const size_t hBytes = (size_t)Mp * NH1 * 2;
    char* big = take(2 * hBytes);
    unsigned short* h    = (unsigned short*)big;
    unsigned short* h1   = (unsigned short*)(big + hBytes);
    unsigned short* h2   = h2r;

    // ---- CSR build: atomic degree count + scan + atomic-cursor placement ----
    hipMemsetAsync(degi, 0, (size_t)N * 4, stream);
    {
        const int degBlocks = (E + 255) / 256;                  // 3125
        const int cvtBlocks = (NFEAT * NH1 + NH1 * NH2 + 255) / 256;  // 640
        k_deg_cvtw<<<degBlocks + cvtBlocks, 256, 0, stream>>>(
            dstp, degi, W1, W1t, W2, W2t, E, degBlocks);
    }
    k_scan1<<<nScanBlocks, SCAN_BLOCK, 0, stream>>>(degi, blocksums, dinv, N);
    k_scan2<<<1, 1024, 0, stream>>>(blocksums, blockoffs, row_start, nScanBlocks, N);
    k_scan3<<<nScanBlocks, SCAN_BLOCK, 0, stream>>>(degi, blockoffs, row_start, N);
    k_place2<<<(E + 255) / 256, 256, 0, stream>>>(srcp, dstp, row_start, csr_src, E);

    // ---- layer 1: h = (x*dinv)@W1 fused (bf16) ; h1 = relu(...)*dinv (bf16) ----
    gemm_x_fused<<<Mp / 128, 512, 0, stream>>>(x, dinv, W1t, h, N, NFEAT);
    {
        int total = N * 64;
        k_gather<NH1, true, false><<<(total + 255) / 256, 256, 0, stream>>>(
            row_start, csr_src, dinv, h, b1, h1, nullptr, N);
    }

    // ---- layer 2: h2 = h1s@W2 (bf16) ; out = gather + b2 (fp32) ----
    {
        dim3 g(NH2 / 128, Mp / 128);
        gemm_bf16<<<g, 256, 0, stream>>>(h1, W2t, h2, NH2, NH1);
    }
    {
        int total = N * 64;
        k_gather<NH2, false, true><<<(total + 255) / 256, 256, 0, stream>>>(
            row_start, csr_src, dinv, h2, b2, nullptr, out, N);
    }
}

// Round 4
// 327.128 us; speedup vs baseline: 1.1306x; 1.1306x over previous
//
#include <hip/hip_runtime.h>
#include <cstdint>
#include <cstddef>

#define NFEAT 512
#define NH1   256
#define NH2   128

#define SCAN_BLOCK 256
#define SCAN_ELEMS 4
#define SCAN_TILE  (SCAN_BLOCK * SCAN_ELEMS)   // 1024

#define P_CHUNKS 128          // edge chunks for privatized histogram
#define HHALF    25088        // nodes per half (2*HHALF = 50176 >= N)
#define NP       (2 * HHALF)  // padded node count in hist rows
#define HPB      1024         // threads per hist/place block (16 waves)

typedef __attribute__((ext_vector_type(8))) short short8;
typedef __attribute__((ext_vector_type(4))) float float4v;

__device__ __forceinline__ unsigned short f2bf(float f) {
    unsigned int u = __float_as_uint(f);
    u += 0x7fffu + ((u >> 16) & 1u);   // round-to-nearest-even
    return (unsigned short)(u >> 16);
}
__device__ __forceinline__ float bf2f(unsigned short u) {
    return __uint_as_float(((unsigned int)u) << 16);
}

__device__ __forceinline__ void load_lds16(const void* g, void* l) {
    __builtin_amdgcn_global_load_lds(
        (const __attribute__((address_space(1))) void*)g,
        (__attribute__((address_space(3))) void*)l, 16, 0, 0);
}

// ---------------- CSR build: LDS-privatized counting sort ----------------
// Phase A: per-(chunk,half) histogram in LDS, coalesced write to hist[c][d].
// 1024 threads: 16 waves/CU for latency hiding (100KB LDS -> 1 block/CU).
__global__ __launch_bounds__(HPB) void k_hist(const int* __restrict__ dst,
                                              int* __restrict__ hist, int E, int CE) {
    __shared__ int lh[HHALF];
    const int c    = blockIdx.x >> 1;
    const int hf   = blockIdx.x & 1;
    const int base = hf * HHALF;
    for (int i = threadIdx.x; i < HHALF; i += HPB) lh[i] = 0;
    __syncthreads();
    const int lo = c * CE;
    const int hi = lo + CE < E ? lo + CE : E;
    for (int e = lo + (int)threadIdx.x; e < hi; e += HPB) {
        const int d = dst[e] - base;
        if ((unsigned)d < (unsigned)HHALF) atomicAdd(&lh[d], 1);
    }
    __syncthreads();
    int* outp = hist + (size_t)c * NP + base;
    for (int i = threadIdx.x; i < HHALF; i += HPB) outp[i] = lh[i];
}

// Phase B: degi[d] = sum_c hist[c][d]; fused dinv = rsqrt(deg+1).
__global__ void k_colreduce(const int* __restrict__ hist, int* __restrict__ degi,
                            float* __restrict__ dinv, int N) {
    const int d = blockIdx.x * blockDim.x + threadIdx.x;
    if (d >= N) return;
    int s = 0;
#pragma unroll 8
    for (int c = 0; c < P_CHUNKS; ++c) s += hist[(size_t)c * NP + d];
    degi[d] = s;
    dinv[d] = rsqrtf((float)(s + 1));   // +1 = self-loop
}

// Phase D: in-place column exclusive scan: hist[c][d] -> global base offset.
__global__ void k_coloffs(int* __restrict__ hist, const int* __restrict__ row_start,
                          int N) {
    const int d = blockIdx.x * blockDim.x + threadIdx.x;
    if (d >= N) return;
    int run = row_start[d];
    for (int c = 0; c < P_CHUNKS; ++c) {
        int* p = &hist[(size_t)c * NP + d];
        const int t = *p;
        *p = run;
        run += t;
    }
}

// Phase E: place edges. LDS cursor atomics only; plain scattered stores.
__global__ __launch_bounds__(HPB) void k_place(const int* __restrict__ src,
                                               const int* __restrict__ dst,
                                               const int* __restrict__ hist,
                                               int* __restrict__ csr_src, int E, int CE) {
    __shared__ int lcur[HHALF];
    const int c    = blockIdx.x >> 1;
    const int hf   = blockIdx.x & 1;
    const int base = hf * HHALF;
    const int* offp = hist + (size_t)c * NP + base;
    for (int i = threadIdx.x; i < HHALF; i += HPB) lcur[i] = offp[i];
    __syncthreads();
    const int lo = c * CE;
    const int hi = lo + CE < E ? lo + CE : E;
    for (int e = lo + (int)threadIdx.x; e < hi; e += HPB) {
        const int d = dst[e] - base;
        if ((unsigned)d < (unsigned)HHALF) {
            const int p = atomicAdd(&lcur[d], 1);   // LDS atomic (fast)
            csr_src[p] = src[e];
        }
    }
}

// ---- three-phase exclusive scan over degi[0..N) -> row_start ----
__global__ __launch_bounds__(SCAN_BLOCK) void k_scan1(
    const int* __restrict__ degi, int* __restrict__ blocksums, int N) {
    __shared__ int red[SCAN_BLOCK];
    const int t = threadIdx.x;
    const int base = blockIdx.x * SCAN_TILE + t * SCAN_ELEMS;
    int s = 0;
#pragma unroll
    for (int i = 0; i < SCAN_ELEMS; ++i) {
        const int idx = base + i;
        if (idx < N) s += degi[idx];
    }
    red[t] = s;
    __syncthreads();
    for (int off = SCAN_BLOCK / 2; off > 0; off >>= 1) {
        if (t < off) red[t] += red[t + off];
        __syncthreads();
    }
    if (t == 0) blocksums[blockIdx.x] = red[0];
}

__global__ __launch_bounds__(1024) void k_scan2(
    const int* __restrict__ blocksums, int* __restrict__ blockoffs,
    int* __restrict__ row_start, int nb, int N) {
    __shared__ int sm[1024];
    const int t = threadIdx.x;
    const int v = (t < nb) ? blocksums[t] : 0;
    sm[t] = v;
    __syncthreads();
    for (int off = 1; off < 1024; off <<= 1) {
        const int x = (t >= off) ? sm[t - off] : 0;
        __syncthreads();
        sm[t] += x;
        __syncthreads();
    }
    if (t < nb) blockoffs[t] = sm[t] - v;
    if (t == 1023) row_start[N] = sm[1023];
}

__global__ __launch_bounds__(SCAN_BLOCK) void k_scan3(
    const int* __restrict__ degi, const int* __restrict__ blockoffs,
    int* __restrict__ row_start, int N) {
    __shared__ int tsum[SCAN_BLOCK];
    const int t = threadIdx.x;
    const int base = blockIdx.x * SCAN_TILE + t * SCAN_ELEMS;
    int v[SCAN_ELEMS];
    int s = 0;
#pragma unroll
    for (int i = 0; i < SCAN_ELEMS; ++i) {
        const int idx = base + i;
        v[i] = (idx < N) ? degi[idx] : 0;
        s += v[i];
    }
    tsum[t] = s;
    __syncthreads();
    for (int off = 1; off < SCAN_BLOCK; off <<= 1) {
        const int x = (t >= off) ? tsum[t - off] : 0;
        __syncthreads();
        tsum[t] += x;
        __syncthreads();
    }
    int excl = blockoffs[blockIdx.x] + tsum[t] - s;
#pragma unroll
    for (int i = 0; i < SCAN_ELEMS; ++i) {
        const int idx = base + i;
        if (idx < N) row_start[idx] = excl;
        excl += v[i];
    }
}

// ---------------- weight conversion (both layers, one dispatch) ----------------
__global__ void k_cvt_w(const float* __restrict__ W1, unsigned short* __restrict__ W1t,
                        const float* __restrict__ W2, unsigned short* __restrict__ W2t) {
    const int i = blockIdx.x * blockDim.x + threadIdx.x;
    const int T1 = NFEAT * NH1;
    const int T2 = NH1 * NH2;
    if (i < T1) {
        const int k = i / NH1, n = i % NH1;
        W1t[(size_t)n * NFEAT + k] = f2bf(W1[i]);
    } else if (i < T1 + T2) {
        const int j = i - T1;
        const int k = j / NH2, n = j % NH2;
        W2t[(size_t)n * NH1 + k] = f2bf(W2[j]);
    }
}

// ---------------- fused layer-1 GEMM: h = bf16((x*dinv) @ W1) ----------------
// 128x256 tile, 8 waves (512 thr). A is reg-staged f32 -> *dinv -> bf16 -> LDS;
// B (W1t, 256x512 bf16 n-major) via global_load_lds. Single column block: A read once.
__global__ __launch_bounds__(512) void gemm_x_fused(
    const float* __restrict__ x, const float* __restrict__ dinv,
    const unsigned short* __restrict__ Bt, unsigned short* __restrict__ C,
    int Nrows, int K) {
    __shared__ unsigned short As[128 * 32];   //  8 KB
    __shared__ unsigned short Bs[256 * 32];   // 16 KB
    const int t    = threadIdx.x;
    const int wave = t >> 6, lane = t & 63;
    const int row0 = blockIdx.x * 128;
    const int quad = lane >> 4, l15 = lane & 15;
    const int wm = (wave >> 2) * 64;          // 0 / 64
    const int wn = (wave & 3) * 64;           // 0 / 64 / 128 / 192

    // A staging: thread t -> row t>>2 (0..127), k-offset (t&3)*8 (8 f32)
    const int arow = t >> 2;
    const int ak   = (t & 3) * 8;
    const int gr   = (row0 + arow < Nrows) ? row0 + arow : Nrows - 1;  // clamp pad rows
    const float wd = dinv[gr];
    const float* gx = x + (size_t)gr * K + ak;
    unsigned short* lA = &As[arow * 32 + ak];                 // byte off = t*16 (linear)

    // B staging: two global_load_lds segs; linear LDS [256][32] matches t*16 layout
    const int brow = t >> 2;                  // 0..127 (seg2: +128)
    const int bk   = (t & 3) * 8;
    const unsigned short* gB0 = Bt + (size_t)brow * K + bk;
    const unsigned short* gB1 = Bt + (size_t)(128 + brow) * K + bk;
    unsigned short* lB0 = &Bs[wave * 512];            // wave-uniform base + lane*16
    unsigned short* lB1 = &Bs[128 * 32 + wave * 512];

    float4v acc[4][4] = {};

    for (int k0 = 0; k0 < K; k0 += 32) {
        __syncthreads();
        load_lds16(gB0 + k0, lB0);
        load_lds16(gB1 + k0, lB1);
        const float4 v0 = *(const float4*)(gx + k0);
        const float4 v1 = *(const float4*)(gx + k0 + 4);
        short8 o;
        o[0] = (short)f2bf(v0.x * wd); o[1] = (short)f2bf(v0.y * wd);
        o[2] = (short)f2bf(v0.z * wd); o[3] = (short)f2bf(v0.w * wd);
        o[4] = (short)f2bf(v1.x * wd); o[5] = (short)f2bf(v1.y * wd);
        o[6] = (short)f2bf(v1.z * wd); o[7] = (short)f2bf(v1.w * wd);
        *(short8*)lA = o;                                   // 16B ds_write
        __syncthreads();

        short8 a[4], b[4];
#pragma unroll
        for (int i = 0; i < 4; ++i) {
            a[i] = *(const short8*)&As[(wm + i * 16 + l15) * 32 + quad * 8];
            b[i] = *(const short8*)&Bs[(wn + i * 16 + l15) * 32 + quad * 8];
        }
#pragma unroll
        for (int mt = 0; mt < 4; ++mt)
#pragma unroll
            for (int nt = 0; nt < 4; ++nt)
                acc[mt][nt] = __builtin_amdgcn_mfma_f32_16x16x32_bf16(
                    a[mt], b[nt], acc[mt][nt], 0, 0, 0);
    }

    // C/D layout: col = lane&15, row = (lane>>4)*4 + reg   [m89-verified]
#pragma unroll
    for (int mt = 0; mt < 4; ++mt) {
#pragma unroll
        for (int nt = 0; nt < 4; ++nt) {
            const int c = wn + nt * 16 + l15;
#pragma unroll
            for (int r = 0; r < 4; ++r) {
                const int row = row0 + wm + mt * 16 + quad * 4 + r;
                C[(size_t)row * NH1 + c] = f2bf(acc[mt][nt][r]);
            }
        }
    }
}

// ---------------- bf16 MFMA GEMM (layer 2) ----------------
__global__ __launch_bounds__(256) void gemm_bf16(
    const unsigned short* __restrict__ A, const unsigned short* __restrict__ Bt,
    unsigned short* __restrict__ C, int N, int K) {
    __shared__ unsigned short As[128 * 32];
    __shared__ unsigned short Bs[128 * 32];
    const int t    = threadIdx.x;
    const int wave = t >> 6, lane = t & 63;
    const int row0 = blockIdx.y * 128, col0 = blockIdx.x * 128;
    const int wm = (wave >> 1) * 64, wn = (wave & 1) * 64;
    const int sr = lane >> 2;
    const int sk = (lane & 3) * 8;
    const int quad = lane >> 4, l15 = lane & 15;

    const int ca = wave * 2;
    const unsigned short* gA0 = A  + (size_t)(row0 + ca * 16 + sr) * K + sk;
    const unsigned short* gA1 = gA0 + (size_t)16 * K;
    const unsigned short* gB0 = Bt + (size_t)(col0 + ca * 16 + sr) * K + sk;
    const unsigned short* gB1 = gB0 + (size_t)16 * K;
    unsigned short* lA0 = &As[ca * 512];
    unsigned short* lA1 = &As[(ca + 1) * 512];
    unsigned short* lB0 = &Bs[ca * 512];
    unsigned short* lB1 = &Bs[(ca + 1) * 512];

    float4v acc[4][4] = {};

    for (int k0 = 0; k0 < K; k0 += 32) {
        __syncthreads();
        load_lds16(gA0 + k0, lA0);
        load_lds16(gA1 + k0, lA1);
        load_lds16(gB0 + k0, lB0);
        load_lds16(gB1 + k0, lB1);
        __syncthreads();

        short8 a[4], b[4];
#pragma unroll
        for (int i = 0; i < 4; ++i) {
            a[i] = *(const short8*)&As[(wm + i * 16 + l15) * 32 + quad * 8];
            b[i] = *(const short8*)&Bs[(wn + i * 16 + l15) * 32 + quad * 8];
        }
#pragma unroll
        for (int mt = 0; mt < 4; ++mt)
#pragma unroll
            for (int nt = 0; nt < 4; ++nt)
                acc[mt][nt] = __builtin_amdgcn_mfma_f32_16x16x32_bf16(
                    a[mt], b[nt], acc[mt][nt], 0, 0, 0);
    }

    // C/D layout: col = lane&15, row = (lane>>4)*4 + reg   [m89-verified]
#pragma unroll
    for (int mt = 0; mt < 4; ++mt) {
#pragma unroll
        for (int nt = 0; nt < 4; ++nt) {
            const int c = col0 + wn + nt * 16 + l15;
#pragma unroll
            for (int r = 0; r < 4; ++r) {
                const int row = row0 + wm + mt * 16 + quad * 4 + r;
                C[(size_t)row * N + c] = f2bf(acc[mt][nt][r]);
            }
        }
    }
}

// ---------------- CSR gather aggregation (bf16 features, pre-scaled rows) ----
template <int F, bool RELU, bool OUTF32>
__global__ __launch_bounds__(256) void k_gather(
    const int* __restrict__ row_start, const int* __restrict__ csr_src,
    const float* __restrict__ dinv, const unsigned short* __restrict__ h,
    const float* __restrict__ bias, unsigned short* __restrict__ ob,
    float* __restrict__ of, int N) {
    const int gid  = blockIdx.x * blockDim.x + threadIdx.x;
    const int node = gid >> 6;
    const int lane = gid & 63;
    if (node >= N) return;

    constexpr int EL = F / 64;           // 4 (F=256) or 2 (F=128)
    const float wd = dinv[node];
    const int jb = row_start[node];
    const int je = row_start[node + 1];
    const unsigned short* hl = h + (size_t)lane * EL;

    float acc[EL];
    {   // self-loop term (h already dinv-scaled)
        const unsigned short* hp = hl + (size_t)node * F;
        if (EL == 4) {
            const ushort4 v = *(const ushort4*)hp;
            acc[0] = bf2f(v.x); acc[1] = bf2f(v.y);
            acc[2] = bf2f(v.z); acc[3] = bf2f(v.w);
        } else {
            const ushort2 v = *(const ushort2*)hp;
            acc[0] = bf2f(v.x); acc[1] = bf2f(v.y);
        }
    }

    for (int j0 = jb; j0 < je; j0 += 64) {
        int jj = j0 + lane;
        if (jj >= je) jj = je - 1;
        const int myi = csr_src[jj];
        const int rem = je - j0;
        const int cnt = rem < 64 ? rem : 64;
        int i = 0;
        for (; i + 4 <= cnt; i += 4) {   // 4 independent row loads in flight
            const int s0 = __shfl(myi, i + 0);
            const int s1 = __shfl(myi, i + 1);
            const int s2 = __shfl(myi, i + 2);
            const int s3 = __shfl(myi, i + 3);
            if (EL == 4) {
                const ushort4 v0 = *(const ushort4*)(hl + (size_t)s0 * F);
                const ushort4 v1 = *(const ushort4*)(hl + (size_t)s1 * F);
                const ushort4 v2 = *(const ushort4*)(hl + (size_t)s2 * F);
                const ushort4 v3 = *(const ushort4*)(hl + (size_t)s3 * F);
                acc[0] += bf2f(v0.x) + bf2f(v1.x) + bf2f(v2.x) + bf2f(v3.x);
                acc[1] += bf2f(v0.y) + bf2f(v1.y) + bf2f(v2.y) + bf2f(v3.y);
                acc[2] += bf2f(v0.z) + bf2f(v1.z) + bf2f(v2.z) + bf2f(v3.z);
                acc[3] += bf2f(v0.w) + bf2f(v1.w) + bf2f(v2.w) + bf2f(v3.w);
            } else {
                const ushort2 v0 = *(const ushort2*)(hl + (size_t)s0 * F);
                const ushort2 v1 = *(const ushort2*)(hl + (size_t)s1 * F);
                const ushort2 v2 = *(const ushort2*)(hl + (size_t)s2 * F);
                const ushort2 v3 = *(const ushort2*)(hl + (size_t)s3 * F);
                acc[0] += bf2f(v0.x) + bf2f(v1.x) + bf2f(v2.x) + bf2f(v3.x);
                acc[1] += bf2f(v0.y) + bf2f(v1.y) + bf2f(v2.y) + bf2f(v3.y);
            }
        }
        for (; i < cnt; ++i) {
            const int s = __shfl(myi, i);
            const unsigned short* hp = hl + (size_t)s * F;
            if (EL == 4) {
                const ushort4 v = *(const ushort4*)hp;
                acc[0] += bf2f(v.x); acc[1] += bf2f(v.y);
                acc[2] += bf2f(v.z); acc[3] += bf2f(v.w);
            } else {
                const ushort2 v = *(const ushort2*)hp;
                acc[0] += bf2f(v.x); acc[1] += bf2f(v.y);
            }
        }
    }

#pragma unroll
    for (int i = 0; i < EL; ++i) {
        float v = fmaf(acc[i], wd, bias[lane * EL + i]);
        if (OUTF32) {
            of[(size_t)node * F + lane * EL + i] = v;
        } else {
            if (RELU) v = fmaxf(v, 0.f);
            ob[(size_t)node * F + lane * EL + i] = f2bf(v * wd);  // pre-scale for next layer
        }
    }
}

extern "C" void kernel_launch(void* const* d_in, const int* in_sizes, int n_in,
                              void* d_out, int out_size, void* d_ws, size_t ws_size,
                              hipStream_t stream) {
    const float* x   = (const float*)d_in[0];
    const int*   ei  = (const int*)d_in[1];
    const float* W1  = (const float*)d_in[2];
    const float* b1  = (const float*)d_in[3];
    const float* W2  = (const float*)d_in[4];
    const float* b2  = (const float*)d_in[5];
    float*       out = (float*)d_out;

    const int N = in_sizes[0] / NFEAT;           // 50000
    const int E = in_sizes[1] / 2;               // 800000
    const int Mp = ((N + 127) / 128) * 128;      // 50048
    const int* srcp = ei;
    const int* dstp = ei + E;
    const int nScanBlocks = (N + SCAN_TILE - 1) / SCAN_TILE;   // 49
    const int CE = (E + P_CHUNKS - 1) / P_CHUNKS;              // 6250

    // workspace layout (256B aligned chunks)
    char* wsb = (char*)d_ws;
    auto take = [&](size_t bytes) {
        char* p = wsb;
        wsb += (bytes + 255) & ~(size_t)255;
        return p;
    };
    int*   degi      = (int*)take((size_t)N * 4);
    int*   row_start = (int*)take((size_t)(N + 1) * 4);
    int*   csr_src   = (int*)take((size_t)E * 4);
    int*   blocksums = (int*)take((size_t)1024 * 4);
    int*   blockoffs = (int*)take((size_t)1024 * 4);
    float* dinv      = (float*)take((size_t)N * 4);
    unsigned short* h2r = (unsigned short*)take((size_t)Mp * NFEAT * 2);  // h2 region
    unsigned short* W1t = (unsigned short*)take((size_t)NH1 * NFEAT * 2);
    unsigned short* W2t = (unsigned short*)take((size_t)NH2 * NH1 * 2);
    // union region: hist (25.7 MB, dead before GEMM1) overlaps h + h1 (51.2 MB)
    const size_t hBytes    = (size_t)Mp * NH1 * 2;
    const size_t histBytes = (size_t)P_CHUNKS * NP * 4;
    char* big = take(histBytes > 2 * hBytes ? histBytes : 2 * hBytes);
    int*            hist = (int*)big;
    unsigned short* h    = (unsigned short*)big;
    unsigned short* h1   = (unsigned short*)(big + hBytes);
    unsigned short* h2   = h2r;

    // ---- CSR build (atomic-free) + dinv ----
    k_hist<<<P_CHUNKS * 2, HPB, 0, stream>>>(dstp, hist, E, CE);
    k_colreduce<<<(N + 255) / 256, 256, 0, stream>>>(hist, degi, dinv, N);
    k_scan1<<<nScanBlocks, SCAN_BLOCK, 0, stream>>>(degi, blocksums, N);
    k_scan2<<<1, 1024, 0, stream>>>(blocksums, blockoffs, row_start, nScanBlocks, N);
    k_scan3<<<nScanBlocks, SCAN_BLOCK, 0, stream>>>(degi, blockoffs, row_start, N);
    k_coloffs<<<(N + 255) / 256, 256, 0, stream>>>(hist, row_start, N);
    k_place<<<P_CHUNKS * 2, HPB, 0, stream>>>(srcp, dstp, hist, csr_src, E, CE);

    // ---- weight conversion (one dispatch) ----
    {
        const int total = NFEAT * NH1 + NH1 * NH2;
        k_cvt_w<<<(total + 255) / 256, 256, 0, stream>>>(W1, W1t, W2, W2t);
    }

    // ---- layer 1: h = (x*dinv)@W1 fused (bf16) ; h1 = relu(...)*dinv (bf16) ----
    gemm_x_fused<<<Mp / 128, 512, 0, stream>>>(x, dinv, W1t, h, N, NFEAT);
    {
        int total = N * 64;
        k_gather<NH1, true, false><<<(total + 255) / 256, 256, 0, stream>>>(
            row_start, csr_src, dinv, h, b1, h1, nullptr, N);
    }

    // ---- layer 2: h2 = h1s@W2 (bf16) ; out = gather + b2 (fp32) ----
    {
        dim3 g(NH2 / 128, Mp / 128);
        gemm_bf16<<<g, 256, 0, stream>>>(h1, W2t, h2, NH2, NH1);
    }
    {
        int total = N * 64;
        k_gather<NH2, false, true><<<(total + 255) / 256, 256, 0, stream>>>(
            row_start, csr_src, dinv, h2, b2, nullptr, out, N);
    }
}

// Round 5
// 319.576 us; speedup vs baseline: 1.1573x; 1.0236x over previous
//
#include <hip/hip_runtime.h>
#include <cstdint>
#include <cstddef>

#define NFEAT 512
#define NH1   256
#define NH2   128

#define P_CHUNKS 128          // edge chunks for privatized histogram
#define HHALF    25088        // nodes per half (2*HHALF = 50176 >= N)
#define NP       (2 * HHALF)  // padded node count in hist rows
#define HPB      1024         // threads per hist/place block (16 waves)

typedef __attribute__((ext_vector_type(8))) short short8;
typedef __attribute__((ext_vector_type(4))) float float4v;

__device__ __forceinline__ unsigned short f2bf(float f) {
    unsigned int u = __float_as_uint(f);
    u += 0x7fffu + ((u >> 16) & 1u);   // round-to-nearest-even
    return (unsigned short)(u >> 16);
}
__device__ __forceinline__ float bf2f(unsigned short u) {
    return __uint_as_float(((unsigned int)u) << 16);
}

__device__ __forceinline__ void load_lds16(const void* g, void* l) {
    __builtin_amdgcn_global_load_lds(
        (const __attribute__((address_space(1))) void*)g,
        (__attribute__((address_space(3))) void*)l, 16, 0, 0);
}

// ---------------- CSR build: LDS-privatized counting sort ----------------
// Phase A: per-(chunk,half) histogram in LDS + weight conversion piggybacked
// as extra blocks (independent work; fills CUs during the hist tail).
__global__ __launch_bounds__(HPB) void k_hist_cvtw(
    const int* __restrict__ dst, int* __restrict__ hist,
    const float* __restrict__ W1, unsigned short* __restrict__ W1t,
    const float* __restrict__ W2, unsigned short* __restrict__ W2t,
    int E, int CE, int HB) {
    __shared__ int lh[HHALF];
    if (blockIdx.x >= HB) {   // weight-conversion blocks (uniform branch)
        const int i = (blockIdx.x - HB) * HPB + (int)threadIdx.x;
        const int T1 = NFEAT * NH1;
        const int T2 = NH1 * NH2;
        if (i < T1) {
            const int k = i / NH1, n = i % NH1;
            W1t[(size_t)n * NFEAT + k] = f2bf(W1[i]);
        } else if (i < T1 + T2) {
            const int j = i - T1;
            const int k = j / NH2, n = j % NH2;
            W2t[(size_t)n * NH1 + k] = f2bf(W2[j]);
        }
        return;
    }
    const int c    = blockIdx.x >> 1;
    const int hf   = blockIdx.x & 1;
    const int base = hf * HHALF;
    for (int i = threadIdx.x; i < HHALF; i += HPB) lh[i] = 0;
    __syncthreads();
    const int lo = c * CE;
    const int hi = lo + CE < E ? lo + CE : E;
    for (int e = lo + (int)threadIdx.x; e < hi; e += HPB) {
        const int d = dst[e] - base;
        if ((unsigned)d < (unsigned)HHALF) atomicAdd(&lh[d], 1);
    }
    __syncthreads();
    int* outp = hist + (size_t)c * NP + base;
    for (int i = threadIdx.x; i < HHALF; i += HPB) outp[i] = lh[i];
}

// Fused: column-reduce hist -> degi, dinv ; block partial sums -> blocksums.
// One thread per node d; 256-wide blocks (tile = 256 nodes).
__global__ __launch_bounds__(256) void k_redscan1(
    const int* __restrict__ hist, int* __restrict__ degi,
    float* __restrict__ dinv, int* __restrict__ blocksums, int N) {
    __shared__ int red[256];
    const int t = threadIdx.x;
    const int d = blockIdx.x * 256 + t;
    int s = 0;
    if (d < N) {
#pragma unroll 8
        for (int c = 0; c < P_CHUNKS; ++c) s += hist[(size_t)c * NP + d];
        degi[d] = s;
        dinv[d] = rsqrtf((float)(s + 1));   // +1 = self-loop
    }
    red[t] = s;
    __syncthreads();
    for (int off = 128; off > 0; off >>= 1) {
        if (t < off) red[t] += red[t + off];
        __syncthreads();
    }
    if (t == 0) blocksums[blockIdx.x] = red[0];
}

__global__ __launch_bounds__(1024) void k_scan2(
    const int* __restrict__ blocksums, int* __restrict__ blockoffs,
    int* __restrict__ row_start, int nb, int N) {
    __shared__ int sm[1024];
    const int t = threadIdx.x;
    const int v = (t < nb) ? blocksums[t] : 0;
    sm[t] = v;
    __syncthreads();
    for (int off = 1; off < 1024; off <<= 1) {
        const int x = (t >= off) ? sm[t - off] : 0;
        __syncthreads();
        sm[t] += x;
        __syncthreads();
    }
    if (t < nb) blockoffs[t] = sm[t] - v;
    if (t == 1023) row_start[N] = sm[1023];
}

// Fused: final scan -> row_start[d], then in-place column exclusive scan of
// hist[c][d] into global base offsets (what k_coloffs did).
__global__ __launch_bounds__(256) void k_scan3off(
    const int* __restrict__ degi, const int* __restrict__ blockoffs,
    int* __restrict__ row_start, int* __restrict__ hist, int N) {
    __shared__ int tsum[256];
    const int t = threadIdx.x;
    const int d = blockIdx.x * 256 + t;
    const int v = (d < N) ? degi[d] : 0;
    tsum[t] = v;
    __syncthreads();
    for (int off = 1; off < 256; off <<= 1) {
        const int x = (t >= off) ? tsum[t - off] : 0;
        __syncthreads();
        tsum[t] += x;
        __syncthreads();
    }
    if (d < N) {
        int run = blockoffs[blockIdx.x] + tsum[t] - v;   // exclusive prefix
        row_start[d] = run;
        for (int c = 0; c < P_CHUNKS; ++c) {
            int* p = &hist[(size_t)c * NP + d];
            const int tt = *p;
            *p = run;
            run += tt;
        }
    }
}

// Phase E: place edges. LDS cursor atomics only; plain scattered stores.
__global__ __launch_bounds__(HPB) void k_place(const int* __restrict__ src,
                                               const int* __restrict__ dst,
                                               const int* __restrict__ hist,
                                               int* __restrict__ csr_src, int E, int CE) {
    __shared__ int lcur[HHALF];
    const int c    = blockIdx.x >> 1;
    const int hf   = blockIdx.x & 1;
    const int base = hf * HHALF;
    const int* offp = hist + (size_t)c * NP + base;
    for (int i = threadIdx.x; i < HHALF; i += HPB) lcur[i] = offp[i];
    __syncthreads();
    const int lo = c * CE;
    const int hi = lo + CE < E ? lo + CE : E;
    for (int e = lo + (int)threadIdx.x; e < hi; e += HPB) {
        const int d = dst[e] - base;
        if ((unsigned)d < (unsigned)HHALF) {
            const int p = atomicAdd(&lcur[d], 1);   // LDS atomic (fast)
            csr_src[p] = src[e];
        }
    }
}

// ---------------- fused layer-1 GEMM: h = bf16((x*dinv) @ W1) ----------------
// 128x256 tile, 8 waves (512 thr). A is reg-staged f32 -> *dinv -> bf16 -> LDS;
// B (W1t, 256x512 bf16 n-major) via global_load_lds. Single column block: A read once.
__global__ __launch_bounds__(512) void gemm_x_fused(
    const float* __restrict__ x, const float* __restrict__ dinv,
    const unsigned short* __restrict__ Bt, unsigned short* __restrict__ C,
    int Nrows, int K) {
    __shared__ unsigned short As[128 * 32];   //  8 KB
    __shared__ unsigned short Bs[256 * 32];   // 16 KB
    const int t    = threadIdx.x;
    const int wave = t >> 6, lane = t & 63;
    const int row0 = blockIdx.x * 128;
    const int quad = lane >> 4, l15 = lane & 15;
    const int wm = (wave >> 2) * 64;          // 0 / 64
    const int wn = (wave & 3) * 64;           // 0 / 64 / 128 / 192

    const int arow = t >> 2;
    const int ak   = (t & 3) * 8;
    const int gr   = (row0 + arow < Nrows) ? row0 + arow : Nrows - 1;  // clamp pad rows
    const float wd = dinv[gr];
    const float* gx = x + (size_t)gr * K + ak;
    unsigned short* lA = &As[arow * 32 + ak];                 // byte off = t*16 (linear)

    const int brow = t >> 2;                  // 0..127 (seg2: +128)
    const int bk   = (t & 3) * 8;
    const unsigned short* gB0 = Bt + (size_t)brow * K + bk;
    const unsigned short* gB1 = Bt + (size_t)(128 + brow) * K + bk;
    unsigned short* lB0 = &Bs[wave * 512];            // wave-uniform base + lane*16
    unsigned short* lB1 = &Bs[128 * 32 + wave * 512];

    float4v acc[4][4] = {};

    for (int k0 = 0; k0 < K; k0 += 32) {
        __syncthreads();
        load_lds16(gB0 + k0, lB0);
        load_lds16(gB1 + k0, lB1);
        const float4 v0 = *(const float4*)(gx + k0);
        const float4 v1 = *(const float4*)(gx + k0 + 4);
        short8 o;
        o[0] = (short)f2bf(v0.x * wd); o[1] = (short)f2bf(v0.y * wd);
        o[2] = (short)f2bf(v0.z * wd); o[3] = (short)f2bf(v0.w * wd);
        o[4] = (short)f2bf(v1.x * wd); o[5] = (short)f2bf(v1.y * wd);
        o[6] = (short)f2bf(v1.z * wd); o[7] = (short)f2bf(v1.w * wd);
        *(short8*)lA = o;                                   // 16B ds_write
        __syncthreads();

        short8 a[4], b[4];
#pragma unroll
        for (int i = 0; i < 4; ++i) {
            a[i] = *(const short8*)&As[(wm + i * 16 + l15) * 32 + quad * 8];
            b[i] = *(const short8*)&Bs[(wn + i * 16 + l15) * 32 + quad * 8];
        }
#pragma unroll
        for (int mt = 0; mt < 4; ++mt)
#pragma unroll
            for (int nt = 0; nt < 4; ++nt)
                acc[mt][nt] = __builtin_amdgcn_mfma_f32_16x16x32_bf16(
                    a[mt], b[nt], acc[mt][nt], 0, 0, 0);
    }

    // C/D layout: col = lane&15, row = (lane>>4)*4 + reg   [m89-verified]
#pragma unroll
    for (int mt = 0; mt < 4; ++mt) {
#pragma unroll
        for (int nt = 0; nt < 4; ++nt) {
            const int c = wn + nt * 16 + l15;
#pragma unroll
            for (int r = 0; r < 4; ++r) {
                const int row = row0 + wm + mt * 16 + quad * 4 + r;
                C[(size_t)row * NH1 + c] = f2bf(acc[mt][nt][r]);
            }
        }
    }
}

// ---------------- bf16 MFMA GEMM (layer 2) ----------------
__global__ __launch_bounds__(256) void gemm_bf16(
    const unsigned short* __restrict__ A, const unsigned short* __restrict__ Bt,
    unsigned short* __restrict__ C, int N, int K) {
    __shared__ unsigned short As[128 * 32];
    __shared__ unsigned short Bs[128 * 32];
    const int t    = threadIdx.x;
    const int wave = t >> 6, lane = t & 63;
    const int row0 = blockIdx.y * 128, col0 = blockIdx.x * 128;
    const int wm = (wave >> 1) * 64, wn = (wave & 1) * 64;
    const int sr = lane >> 2;
    const int sk = (lane & 3) * 8;
    const int quad = lane >> 4, l15 = lane & 15;

    const int ca = wave * 2;
    const unsigned short* gA0 = A  + (size_t)(row0 + ca * 16 + sr) * K + sk;
    const unsigned short* gA1 = gA0 + (size_t)16 * K;
    const unsigned short* gB0 = Bt + (size_t)(col0 + ca * 16 + sr) * K + sk;
    const unsigned short* gB1 = gB0 + (size_t)16 * K;
    unsigned short* lA0 = &As[ca * 512];
    unsigned short* lA1 = &As[(ca + 1) * 512];
    unsigned short* lB0 = &Bs[ca * 512];
    unsigned short* lB1 = &Bs[(ca + 1) * 512];

    float4v acc[4][4] = {};

    for (int k0 = 0; k0 < K; k0 += 32) {
        __syncthreads();
        load_lds16(gA0 + k0, lA0);
        load_lds16(gA1 + k0, lA1);
        load_lds16(gB0 + k0, lB0);
        load_lds16(gB1 + k0, lB1);
        __syncthreads();

        short8 a[4], b[4];
#pragma unroll
        for (int i = 0; i < 4; ++i) {
            a[i] = *(const short8*)&As[(wm + i * 16 + l15) * 32 + quad * 8];
            b[i] = *(const short8*)&Bs[(wn + i * 16 + l15) * 32 + quad * 8];
        }
#pragma unroll
        for (int mt = 0; mt < 4; ++mt)
#pragma unroll
            for (int nt = 0; nt < 4; ++nt)
                acc[mt][nt] = __builtin_amdgcn_mfma_f32_16x16x32_bf16(
                    a[mt], b[nt], acc[mt][nt], 0, 0, 0);
    }

    // C/D layout: col = lane&15, row = (lane>>4)*4 + reg   [m89-verified]
#pragma unroll
    for (int mt = 0; mt < 4; ++mt) {
#pragma unroll
        for (int nt = 0; nt < 4; ++nt) {
            const int c = col0 + wn + nt * 16 + l15;
#pragma unroll
            for (int r = 0; r < 4; ++r) {
                const int row = row0 + wm + mt * 16 + quad * 4 + r;
                C[(size_t)row * N + c] = f2bf(acc[mt][nt][r]);
            }
        }
    }
}

// ---------------- CSR gather aggregation (bf16 features, pre-scaled rows) ----
template <int F, bool RELU, bool OUTF32>
__global__ __launch_bounds__(256) void k_gather(
    const int* __restrict__ row_start, const int* __restrict__ csr_src,
    const float* __restrict__ dinv, const unsigned short* __restrict__ h,
    const float* __restrict__ bias, unsigned short* __restrict__ ob,
    float* __restrict__ of, int N) {
    const int gid  = blockIdx.x * blockDim.x + threadIdx.x;
    const int node = gid >> 6;
    const int lane = gid & 63;
    if (node >= N) return;

    constexpr int EL = F / 64;           // 4 (F=256) or 2 (F=128)
    const float wd = dinv[node];
    const int jb = row_start[node];
    const int je = row_start[node + 1];
    const unsigned short* hl = h + (size_t)lane * EL;

    float acc[EL];
    {   // self-loop term (h already dinv-scaled)
        const unsigned short* hp = hl + (size_t)node * F;
        if (EL == 4) {
            const ushort4 v = *(const ushort4*)hp;
            acc[0] = bf2f(v.x); acc[1] = bf2f(v.y);
            acc[2] = bf2f(v.z); acc[3] = bf2f(v.w);
        } else {
            const ushort2 v = *(const ushort2*)hp;
            acc[0] = bf2f(v.x); acc[1] = bf2f(v.y);
        }
    }

    for (int j0 = jb; j0 < je; j0 += 64) {
        int jj = j0 + lane;
        if (jj >= je) jj = je - 1;
        const int myi = csr_src[jj];
        const int rem = je - j0;
        const int cnt = rem < 64 ? rem : 64;
        int i = 0;
        for (; i + 8 <= cnt; i += 8) {   // 8 independent row loads in flight
            int s[8];
#pragma unroll
            for (int u = 0; u < 8; ++u) s[u] = __shfl(myi, i + u);
            if (EL == 4) {
                ushort4 v[8];
#pragma unroll
                for (int u = 0; u < 8; ++u)
                    v[u] = *(const ushort4*)(hl + (size_t)s[u] * F);
#pragma unroll
                for (int u = 0; u < 8; ++u) {
                    acc[0] += bf2f(v[u].x); acc[1] += bf2f(v[u].y);
                    acc[2] += bf2f(v[u].z); acc[3] += bf2f(v[u].w);
                }
            } else {
                ushort2 v[8];
#pragma unroll
                for (int u = 0; u < 8; ++u)
                    v[u] = *(const ushort2*)(hl + (size_t)s[u] * F);
#pragma unroll
                for (int u = 0; u < 8; ++u) {
                    acc[0] += bf2f(v[u].x); acc[1] += bf2f(v[u].y);
                }
            }
        }
        for (; i + 4 <= cnt; i += 4) {
            const int s0 = __shfl(myi, i + 0);
            const int s1 = __shfl(myi, i + 1);
            const int s2 = __shfl(myi, i + 2);
            const int s3 = __shfl(myi, i + 3);
            if (EL == 4) {
                const ushort4 v0 = *(const ushort4*)(hl + (size_t)s0 * F);
                const ushort4 v1 = *(const ushort4*)(hl + (size_t)s1 * F);
                const ushort4 v2 = *(const ushort4*)(hl + (size_t)s2 * F);
                const ushort4 v3 = *(const ushort4*)(hl + (size_t)s3 * F);
                acc[0] += bf2f(v0.x) + bf2f(v1.x) + bf2f(v2.x) + bf2f(v3.x);
                acc[1] += bf2f(v0.y) + bf2f(v1.y) + bf2f(v2.y) + bf2f(v3.y);
                acc[2] += bf2f(v0.z) + bf2f(v1.z) + bf2f(v2.z) + bf2f(v3.z);
                acc[3] += bf2f(v0.w) + bf2f(v1.w) + bf2f(v2.w) + bf2f(v3.w);
            } else {
                const ushort2 v0 = *(const ushort2*)(hl + (size_t)s0 * F);
                const ushort2 v1 = *(const ushort2*)(hl + (size_t)s1 * F);
                const ushort2 v2 = *(const ushort2*)(hl + (size_t)s2 * F);
                const ushort2 v3 = *(const ushort2*)(hl + (size_t)s3 * F);
                acc[0] += bf2f(v0.x) + bf2f(v1.x) + bf2f(v2.x) + bf2f(v3.x);
                acc[1] += bf2f(v0.y) + bf2f(v1.y) + bf2f(v2.y) + bf2f(v3.y);
            }
        }
        for (; i < cnt; ++i) {
            const int s = __shfl(myi, i);
            const unsigned short* hp = hl + (size_t)s * F;
            if (EL == 4) {
                const ushort4 v = *(const ushort4*)hp;
                acc[0] += bf2f(v.x); acc[1] += bf2f(v.y);
                acc[2] += bf2f(v.z); acc[3] += bf2f(v.w);
            } else {
                const ushort2 v = *(const ushort2*)hp;
                acc[0] += bf2f(v.x); acc[1] += bf2f(v.y);
            }
        }
    }

#pragma unroll
    for (int i = 0; i < EL; ++i) {
        float v = fmaf(acc[i], wd, bias[lane * EL + i]);
        if (OUTF32) {
            of[(size_t)node * F + lane * EL + i] = v;
        } else {
            if (RELU) v = fmaxf(v, 0.f);
            ob[(size_t)node * F + lane * EL + i] = f2bf(v * wd);  // pre-scale for next layer
        }
    }
}

extern "C" void kernel_launch(void* const* d_in, const int* in_sizes, int n_in,
                              void* d_out, int out_size, void* d_ws, size_t ws_size,
                              hipStream_t stream) {
    const float* x   = (const float*)d_in[0];
    const int*   ei  = (const int*)d_in[1];
    const float* W1  = (const float*)d_in[2];
    const float* b1  = (const float*)d_in[3];
    const float* W2  = (const float*)d_in[4];
    const float* b2  = (const float*)d_in[5];
    float*       out = (float*)d_out;

    const int N = in_sizes[0] / NFEAT;           // 50000
    const int E = in_sizes[1] / 2;               // 800000
    const int Mp = ((N + 127) / 128) * 128;      // 50048
    const int* srcp = ei;
    const int* dstp = ei + E;
    const int CE = (E + P_CHUNKS - 1) / P_CHUNKS;   // 6250
    const int nRed = (N + 255) / 256;               // 196 (<=1024 for scan2)

    // workspace layout (256B aligned chunks)
    char* wsb = (char*)d_ws;
    auto take = [&](size_t bytes) {
        char* p = wsb;
        wsb += (bytes + 255) & ~(size_t)255;
        return p;
    };
    int*   degi      = (int*)take((size_t)N * 4);
    int*   row_start = (int*)take((size_t)(N + 1) * 4);
    int*   csr_src   = (int*)take((size_t)E * 4);
    int*   blocksums = (int*)take((size_t)1024 * 4);
    int*   blockoffs = (int*)take((size_t)1024 * 4);
    float* dinv      = (float*)take((size_t)N * 4);
    unsigned short* h2r = (unsigned short*)take((size_t)Mp * NH2 * 2);   // h2
    unsigned short* W1t = (unsigned short*)take((size_t)NH1 * NFEAT * 2);
    unsigned short* W2t = (unsigned short*)take((size_t)NH2 * NH1 * 2);
    // union region: hist (25.7 MB, dead before GEMM1) overlaps h + h1 (51.2 MB)
    const size_t hBytes    = (size_t)Mp * NH1 * 2;
    const size_t histBytes = (size_t)P_CHUNKS * NP * 4;
    char* big = take(histBytes > 2 * hBytes ? histBytes : 2 * hBytes);
    int*            hist = (int*)big;
    unsigned short* h    = (unsigned short*)big;
    unsigned short* h1   = (unsigned short*)(big + hBytes);
    unsigned short* h2   = h2r;

    // ---- CSR build (atomic-free) + dinv + weight cvt: 5 dispatches ----
    {
        const int HB = P_CHUNKS * 2;                                    // 256
        const int CB = (NFEAT * NH1 + NH1 * NH2 + HPB - 1) / HPB;       // 160
        k_hist_cvtw<<<HB + CB, HPB, 0, stream>>>(dstp, hist, W1, W1t, W2, W2t,
                                                 E, CE, HB);
    }
    k_redscan1<<<nRed, 256, 0, stream>>>(hist, degi, dinv, blocksums, N);
    k_scan2<<<1, 1024, 0, stream>>>(blocksums, blockoffs, row_start, nRed, N);
    k_scan3off<<<nRed, 256, 0, stream>>>(degi, blockoffs, row_start, hist, N);
    k_place<<<P_CHUNKS * 2, HPB, 0, stream>>>(srcp, dstp, hist, csr_src, E, CE);

    // ---- layer 1: h = (x*dinv)@W1 fused (bf16) ; h1 = relu(...)*dinv (bf16) ----
    gemm_x_fused<<<Mp / 128, 512, 0, stream>>>(x, dinv, W1t, h, N, NFEAT);
    {
        int total = N * 64;
        k_gather<NH1, true, false><<<(total + 255) / 256, 256, 0, stream>>>(
            row_start, csr_src, dinv, h, b1, h1, nullptr, N);
    }

    // ---- layer 2: h2 = h1s@W2 (bf16) ; out = gather + b2 (fp32) ----
    {
        dim3 g(NH2 / 128, Mp / 128);
        gemm_bf16<<<g, 256, 0, stream>>>(h1, W2t, h2, NH2, NH1);
    }
    {
        int total = N * 64;
        k_gather<NH2, false, true><<<(total + 255) / 256, 256, 0, stream>>>(
            row_start, csr_src, dinv, h2, b2, nullptr, out, N);
    }
}